// Round 1
// baseline (89.413 us; speedup 1.0000x reference)
//
#include <hip/hip_runtime.h>
#include <stdint.h>

typedef _Float16 half8 __attribute__((ext_vector_type(8)));
typedef float f32x16 __attribute__((ext_vector_type(16)));

#define NPTS   4096
#define BATCH  16
#define TILES  32                 // p1 tiles per batch, 128 selves each
#define BLOCK  512                // 8 waves: 4 self-groups x 2 g-halves
#define NBLK   (BATCH * TILES)    // 512 blocks -> 2 blocks/CU, 4 waves/SIMD
#define CHUNK  1024               // others staged per pass (2 x 16 KB records)
#define NCHUNK (NPTS / CHUNK)     // 4

// workspace layout (bytes); ws is 256 MB, we use ~2.25 MB
#define REC0_OFF    0                                   // [B*NPTS] half8 (1 MiB)
#define REC1_OFF    (BATCH * NPTS * 16)                 // [B*NPTS] half8 (1 MiB)
#define COLKEY_OFF  (2 * BATCH * NPTS * 16)             // [B*NPTS] u32 keys (256 KiB)
#define ROWPART_OFF (COLKEY_OFF + BATCH * NPTS * 4)     // [NBLK] float

__device__ __forceinline__ void gll16(const void* g, void* l) {
    // async global->LDS, 16B/lane; LDS dest = uniform base + lane*16 (linear)
    __builtin_amdgcn_global_load_lds(
        (const __attribute__((address_space(1))) uint32_t*)g,
        (__attribute__((address_space(3))) uint32_t*)l, 16, 0, 0);
}

// monotone float<->uint key: exact total order, works for negatives
__device__ __forceinline__ uint32_t fkey(float f) {
    uint32_t u = __float_as_uint(f);
    return u ^ ((uint32_t)((int32_t)u >> 31) | 0x80000000u);
}
__device__ __forceinline__ float funkey(uint32_t k) {
    uint32_t u = (k & 0x80000000u) ? (k ^ 0x80000000u) : ~k;
    return __uint_as_float(u);
}

__device__ __forceinline__ float rmin16(f32x16 o) {
    float a = fminf(fminf(o[0],  o[1]),  fminf(o[2],  o[3]));
    float b = fminf(fminf(o[4],  o[5]),  fminf(o[6],  o[7]));
    float c = fminf(fminf(o[8],  o[9]),  fminf(o[10], o[11]));
    float d = fminf(fminf(o[12], o[13]), fminf(o[14], o[15]));
    return fminf(fminf(a, b), fminf(c, d));
}

// ---------------- k0: prebuild B-side records for p2, init colKey ----------
// dist(s,o) = |s|^2 + s.g + |o|^2, g = -2o, all f16 hi/lo split.
// grp0: A=[shx,shy,shz,sshi,sslo,slx,sly,slz] . R0=[ghx,ghy,ghz,1,1,glx,gly,glz]
// grp1: A=[slx,sly,slz,shx,shy,shz,  1,  1 ] . R1=[ghx,ghy,ghz,glx,gly,glz,qh,ql]
// sum over K=16 = sh.gh+sl.gl+sl.gh+sh.gl + (sshi+sslo) + (qh+ql) = full dist.
__global__ __launch_bounds__(256) void chamfer_prep(
    const float* __restrict__ p2, uint8_t* __restrict__ ws)
{
    const int idx = blockIdx.x * 256 + threadIdx.x;       // 0..65535
    const float x = p2[idx * 3], y = p2[idx * 3 + 1], z = p2[idx * 3 + 2];
    const float gx = -2.f * x, gy = -2.f * y, gz = -2.f * z;
    const float q  = fmaf(x, x, fmaf(y, y, z * z));
    _Float16 ghx = (_Float16)gx, ghy = (_Float16)gy, ghz = (_Float16)gz;
    _Float16 glx = (_Float16)(gx - (float)ghx);
    _Float16 gly = (_Float16)(gy - (float)ghy);
    _Float16 glz = (_Float16)(gz - (float)ghz);
    _Float16 qh = (_Float16)q, ql = (_Float16)(q - (float)qh);
    const _Float16 one = (_Float16)1.f;
    half8 r0, r1;
    r0[0]=ghx; r0[1]=ghy; r0[2]=ghz; r0[3]=one; r0[4]=one; r0[5]=glx; r0[6]=gly; r0[7]=glz;
    r1[0]=ghx; r1[1]=ghy; r1[2]=ghz; r1[3]=glx; r1[4]=gly; r1[5]=glz; r1[6]=qh;  r1[7]=ql;
    ((half8*)(ws + REC0_OFF))[idx] = r0;
    ((half8*)(ws + REC1_OFF))[idx] = r1;
    ((uint32_t*)(ws + COLKEY_OFF))[idx] = 0xFFFFFFFFu;    // key(+NaN) = max
}

// ---------------- k1: single pass over dist matrix, both reductions --------
__global__ __launch_bounds__(BLOCK, 4) void chamfer_main(
    const float* __restrict__ p1, uint8_t* __restrict__ ws)
{
    __shared__ half8    R0b[2][CHUNK];     // 32 KB (double-buffered grp0 records)
    __shared__ half8    R1b[2][CHUNK];     // 32 KB
    __shared__ uint32_t colKeyL[NPTS];     // 16 KB  -> 80 KB total = 2 blocks/CU

    const int tid  = threadIdx.x;
    const int lane = tid & 63;
    const int n    = lane & 31;            // MFMA col (other) / A row (self)
    const int grp  = lane >> 5;            // K-group
    const int wv   = tid >> 6;             // 0..7
    const int sg   = wv >> 1;              // self group (32 selves)
    const int gh   = wv & 1;               // which half of each chunk's g-range
    const int blk  = blockIdx.x;
    const int tile = blk & (TILES - 1);
    const int b    = blk >> 5;

    const float* selfp = p1 + (size_t)b * NPTS * 3;

    // ---- A fragment (full distance folded in; see k0 comment) ----
    half8 a;
    {
        const int s = tile * 128 + sg * 32 + n;
        const float x = selfp[s*3], y = selfp[s*3+1], z = selfp[s*3+2];
        const float ss = fmaf(x, x, fmaf(y, y, z * z));
        _Float16 hx = (_Float16)x, hy = (_Float16)y, hz = (_Float16)z;
        _Float16 lx = (_Float16)(x - (float)hx);
        _Float16 ly = (_Float16)(y - (float)hy);
        _Float16 lz = (_Float16)(z - (float)hz);
        _Float16 sh = (_Float16)ss, sl = (_Float16)(ss - (float)sh);
        const _Float16 one = (_Float16)1.f;
        if (grp == 0) { a[0]=hx; a[1]=hy; a[2]=hz; a[3]=sh; a[4]=sl; a[5]=lx; a[6]=ly; a[7]=lz; }
        else          { a[0]=lx; a[1]=ly; a[2]=lz; a[3]=hx; a[4]=hy; a[5]=hz; a[6]=one; a[7]=one; }
    }

    for (int i = tid; i < NPTS; i += BLOCK) colKeyL[i] = 0xFFFFFFFFu;

    f32x16 m0, zc;
#pragma unroll
    for (int r = 0; r < 16; ++r) { m0[r] = 3.4e38f; zc[r] = 0.f; }

    // staging: wave wv copies 4 KB of (wv<4 ? R0 : R1) per chunk, linear
    const uint8_t* gsrcBase = ws + (wv < 4 ? REC0_OFF : REC1_OFF)
                            + (size_t)b * NPTS * 16 + (size_t)(wv & 3) * 4096
                            + (size_t)lane * 16;
    {
        char* l = (char*)(wv < 4 ? &R0b[0][0] : &R1b[0][0]) + (wv & 3) * 4096;
        const uint8_t* g = gsrcBase;
        gll16(g, l); gll16(g + 1024, l + 1024);
        gll16(g + 2048, l + 2048); gll16(g + 3072, l + 3072);
    }
    __syncthreads();   // drains vmcnt before reads

    for (int c = 0; c < NCHUNK; ++c) {
        const int cb = c & 1;
        if (c + 1 < NCHUNK) {   // prefetch next chunk into the other buffer
            char* l = (char*)(wv < 4 ? &R0b[cb ^ 1][0] : &R1b[cb ^ 1][0]) + (wv & 3) * 4096;
            const uint8_t* g = gsrcBase + (size_t)(c + 1) * 16384;
            gll16(g, l); gll16(g + 1024, l + 1024);
            gll16(g + 2048, l + 2048); gll16(g + 3072, l + 3072);
        }
        const half8* rp = (grp ? &R1b[cb][0] : &R0b[cb][0]) + gh * 512 + n;
        const int abase = c * CHUNK + gh * 512 + grp * 32 + n;
#pragma unroll 2
        for (int k = 0; k < 8; ++k) {      // 8 g-rounds x 64 others
            half8 b0 = rp[k * 64];
            half8 b1 = rp[k * 64 + 32];
            f32x16 o0 = __builtin_amdgcn_mfma_f32_32x32x16_f16(a, b0, zc, 0, 0, 0);
            f32x16 o1 = __builtin_amdgcn_mfma_f32_32x32x16_f16(a, b1, zc, 0, 0, 0);
            // row-min (p1 side): each value touched once via v_min3
#pragma unroll
            for (int r = 0; r < 16; ++r)
                m0[r] = fminf(fminf(o0[r], o1[r]), m0[r]);
            // col-min (p2 side): min over this wave's 32 selves
            float c0 = rmin16(o0), c1 = rmin16(o1);
            c0 = fminf(c0, __shfl_xor(c0, 32));    // join the two row-halves
            c1 = fminf(c1, __shfl_xor(c1, 32));
            const float cm = grp ? c1 : c0;        // lane owns one column
            atomicMin(&colKeyL[abase + k * 64], fkey(cm));
        }
        __syncthreads();
    }

    // ---- epilogue ----
    // row: reduce m0 across the 32 columns each lane-group covered
#pragma unroll
    for (int mask = 1; mask <= 16; mask <<= 1)
#pragma unroll
        for (int r = 0; r < 16; ++r)
            m0[r] = fminf(m0[r], __shfl_xor((float)m0[r], mask));

    float* rowminL = (float*)&R0b[0][0];   // reuse: all LDS reads done (barrier above)
    if ((lane & 31) == 0) {
        const int h = lane >> 5;
#pragma unroll
        for (int r = 0; r < 16; ++r)
            rowminL[wv * 32 + (r & 3) + 8 * (r >> 2) + 4 * h] = m0[r];
    }
    // col: one global atomic per (block, other)
    uint32_t* colKeyG = (uint32_t*)(ws + COLKEY_OFF) + (size_t)b * NPTS;
#pragma unroll
    for (int i = 0; i < NPTS / BLOCK; ++i) {
        const int m = tid + i * BLOCK;
        atomicMin(&colKeyG[m], colKeyL[m]);
    }
    __syncthreads();

    float* psum = (float*)&R1b[0][0];
    if (tid < 128) {   // combine the gh-pair per row, then block-sum
        const int sg2 = tid >> 5, row = tid & 31;
        float v = fminf(rowminL[(sg2 * 2) * 32 + row],
                        rowminL[(sg2 * 2 + 1) * 32 + row]);
#pragma unroll
        for (int off = 32; off; off >>= 1) v += __shfl_down(v, off);
        if ((tid & 63) == 0) psum[tid >> 6] = v;
    }
    __syncthreads();
    if (tid == 0)
        ((float*)(ws + ROWPART_OFF))[blk] = psum[0] + psum[1];
}

// ---------------- k2: deterministic final reduction ------------------------
__global__ __launch_bounds__(512) void chamfer_final(
    const uint8_t* __restrict__ ws, float* __restrict__ out)
{
    const uint4* ck = (const uint4*)(ws + COLKEY_OFF);          // 16384 quads
    const float* rowpart = (const float*)(ws + ROWPART_OFF);    // 512 floats
    const int tid = threadIdx.x;
    float s = 0.f;
#pragma unroll
    for (int i = 0; i < 32; ++i) {
        uint4 v = ck[tid + i * 512];
        s += funkey(v.x) + funkey(v.y) + funkey(v.z) + funkey(v.w);
    }
    s += rowpart[tid];
#pragma unroll
    for (int off = 32; off; off >>= 1) s += __shfl_down(s, off);
    __shared__ float wsum[8];
    if ((tid & 63) == 0) wsum[tid >> 6] = s;
    __syncthreads();
    if (tid == 0) {
        float t = 0.f;
#pragma unroll
        for (int i = 0; i < 8; ++i) t += wsum[i];
        out[0] = t * (1.0f / BATCH);
    }
}

extern "C" void kernel_launch(void* const* d_in, const int* in_sizes, int n_in,
                              void* d_out, int out_size, void* d_ws, size_t ws_size,
                              hipStream_t stream) {
    const float* p1 = (const float*)d_in[0];
    const float* p2 = (const float*)d_in[1];
    uint8_t* ws = (uint8_t*)d_ws;
    chamfer_prep<<<dim3(256), dim3(256), 0, stream>>>(p2, ws);
    chamfer_main<<<dim3(NBLK), dim3(BLOCK), 0, stream>>>(p1, ws);
    chamfer_final<<<dim3(1), dim3(512), 0, stream>>>(ws, (float*)d_out);
}

// Round 2
// 78.020 us; speedup vs baseline: 1.1460x; 1.1460x over previous
//
#include <hip/hip_runtime.h>
#include <stdint.h>

typedef _Float16 half8 __attribute__((ext_vector_type(8)));
typedef float f32x16 __attribute__((ext_vector_type(16)));

#define NPTS   4096
#define BATCH  16
#define BLOCK  256                 // 4 waves x 32 selves = 128 selves/block
#define TILES  32                  // 4096 / 128
#define NBLK   (2 * BATCH * TILES) // 1024 blocks -> exactly 4 blocks/CU
#define CHUNK  1024                // others per LDS pass
#define NCHUNK (NPTS / CHUNK)      // 4

// workspace layout (bytes): REC[2][BATCH][NPTS] half8 (2 MiB), then partials
#define REC_OFF  0
#define PART_OFF (2 * BATCH * NPTS * 16)

__device__ __forceinline__ void gll16(const void* g, void* l) {
    // async global->LDS: LDS dest = wave-uniform base + lane*16 (linear)
    __builtin_amdgcn_global_load_lds(
        (const __attribute__((address_space(1))) uint32_t*)g,
        (__attribute__((address_space(3))) uint32_t*)l, 16, 0, 0);
}

// ---------------- k0: prebuild 16-B records for both point sets ------------
// dist(s,o) = |s|^2 + (s.g + q), g = -2o, q = |o|^2, f16 hi/lo split.
// Record R = [ghx,ghy,ghz,glx,gly,glz,qh,ql]; both K-groups read the SAME
// record, the A-fragment differs per group (exact round-0 math, absmax 0):
//   grp0: A=[shx,shy,shz,0,0,0,1,0]          -> sh.gh + qh
//   grp1: A=[slx,sly,slz,shx,shy,shz,0,1]    -> sl.gh + sh.gl + ql
// |s|^2 is added per row in the epilogue (row-min only -> valid).
__global__ __launch_bounds__(256) void chamfer_prep(
    const float* __restrict__ p1, const float* __restrict__ p2,
    uint8_t* __restrict__ ws)
{
    const int idx  = blockIdx.x * 256 + threadIdx.x;   // 0 .. 2*B*NPTS-1
    const int half = idx >> 16;                        // 0: others=p2, 1: others=p1
    const int i    = idx & (BATCH * NPTS - 1);
    const float* src = half ? p1 : p2;
    const float x = src[i * 3], y = src[i * 3 + 1], z = src[i * 3 + 2];
    const float gx = -2.f * x, gy = -2.f * y, gz = -2.f * z;
    const float q  = fmaf(x, x, fmaf(y, y, z * z));
    _Float16 ghx = (_Float16)gx, ghy = (_Float16)gy, ghz = (_Float16)gz;
    half8 r;
    r[0] = ghx; r[1] = ghy; r[2] = ghz;
    r[3] = (_Float16)(gx - (float)ghx);
    r[4] = (_Float16)(gy - (float)ghy);
    r[5] = (_Float16)(gz - (float)ghz);
    _Float16 qh = (_Float16)q;
    r[6] = qh;
    r[7] = (_Float16)(q - (float)qh);
    ((half8*)(ws + REC_OFF))[idx] = r;
}

// ---------------- k1: row-min pass (run per direction via blockIdx) --------
__global__ __launch_bounds__(BLOCK, 4) void chamfer_main(
    const float* __restrict__ p1, const float* __restrict__ p2,
    uint8_t* __restrict__ ws)
{
    __shared__ half8 RECL[2][CHUNK];   // 32 KB -> 4 blocks/CU, 4 waves/SIMD

    const int tid  = threadIdx.x;
    const int lane = tid & 63;
    const int n    = lane & 31;        // A row (self) / output col (other)
    const int grp  = lane >> 5;        // K-group
    const int wv   = tid >> 6;         // 0..3
    const int blk  = blockIdx.x;
    const int tile = blk & (TILES - 1);
    const int b    = (blk >> 5) & (BATCH - 1);
    const int dir  = blk >> 9;

    const float* selfp = (dir == 0 ? p1 : p2) + (size_t)b * NPTS * 3;

    // ---- A fragment: 32 selves per wave ----
    half8 a; float ssq;
    {
        const int s = tile * 128 + wv * 32 + n;
        const float x = selfp[s * 3], y = selfp[s * 3 + 1], z = selfp[s * 3 + 2];
        ssq = fmaf(x, x, fmaf(y, y, z * z));
        _Float16 hx = (_Float16)x, hy = (_Float16)y, hz = (_Float16)z;
        _Float16 lx = (_Float16)(x - (float)hx);
        _Float16 ly = (_Float16)(y - (float)hy);
        _Float16 lz = (_Float16)(z - (float)hz);
        const _Float16 c0 = (_Float16)0.f, c1 = (_Float16)1.f;
        if (grp == 0) { a[0]=hx; a[1]=hy; a[2]=hz; a[3]=c0; a[4]=c0; a[5]=c0; a[6]=c1; a[7]=c0; }
        else          { a[0]=lx; a[1]=ly; a[2]=lz; a[3]=hx; a[4]=hy; a[5]=hz; a[6]=c0; a[7]=c1; }
    }

    f32x16 m0, zc;
#pragma unroll
    for (int r = 0; r < 16; ++r) { m0[r] = 3.4e38f; zc[r] = 0.f; }

    // staging: each wave copies 4 KB/chunk via 4x width-16 global_load_lds
    const uint8_t* gsrc = ws + REC_OFF
                        + (((size_t)dir * BATCH + b) * NPTS) * 16
                        + (size_t)wv * 4096 + (size_t)lane * 16;
    {
        char* l = (char*)&RECL[0][0] + wv * 4096;
        gll16(gsrc, l);            gll16(gsrc + 1024, l + 1024);
        gll16(gsrc + 2048, l + 2048); gll16(gsrc + 3072, l + 3072);
    }
    __syncthreads();   // barrier drains vmcnt -> chunk 0 ready

    for (int c = 0; c < NCHUNK; ++c) {
        const int cb = c & 1;
        if (c + 1 < NCHUNK) {      // prefetch next chunk; hidden under compute
            char* l = (char*)&RECL[cb ^ 1][0] + wv * 4096;
            const uint8_t* g = gsrc + (size_t)(c + 1) * (CHUNK * 16);
            gll16(g, l);            gll16(g + 1024, l + 1024);
            gll16(g + 2048, l + 2048); gll16(g + 3072, l + 3072);
        }
        const half8* rp = &RECL[cb][0] + n;    // all offsets immediate
#pragma unroll
        for (int g = 0; g < 32; g += 2) {
            half8 b0 = rp[g * 32];
            half8 b1 = rp[g * 32 + 32];
            f32x16 o0 = __builtin_amdgcn_mfma_f32_32x32x16_f16(a, b0, zc, 0, 0, 0);
            f32x16 o1 = __builtin_amdgcn_mfma_f32_32x32x16_f16(a, b1, zc, 0, 0, 0);
#pragma unroll
            for (int r = 0; r < 16; ++r)
                m0[r] = fminf(fminf(o0[r], o1[r]), m0[r]);   // v_min3_f32
        }
        __syncthreads();
    }

    // ---- epilogue: min over the 32 columns, sum rows, one store/wave ----
#pragma unroll
    for (int mask = 1; mask <= 16; mask <<= 1)
#pragma unroll
        for (int r = 0; r < 16; ++r)
            m0[r] = fminf(m0[r], __shfl_xor((float)m0[r], mask));

    float rowsum = 0.f;
#pragma unroll
    for (int r = 0; r < 16; ++r) rowsum += m0[r];
    rowsum += __shfl_xor(rowsum, 32);       // other half's 16 rows

    float sv = grp ? 0.f : ssq;             // each self counted once
#pragma unroll
    for (int mask = 1; mask <= 16; mask <<= 1) sv += __shfl_xor(sv, mask);

    if (lane == 0)
        ((float*)(ws + PART_OFF))[blk * 4 + wv] = rowsum + sv;
}

// ---------------- k2: sum 4096 partials ------------------------------------
__global__ __launch_bounds__(256) void chamfer_reduce(
    const uint8_t* __restrict__ ws, float* __restrict__ out)
{
    const float* partial = (const float*)(ws + PART_OFF);
    float s = 0.f;
#pragma unroll
    for (int i = 0; i < NBLK * 4 / 256; ++i) s += partial[threadIdx.x + i * 256];
#pragma unroll
    for (int off = 32; off; off >>= 1) s += __shfl_down(s, off, 64);
    __shared__ float ws4[4];
    const int lane = threadIdx.x & 63, wv = threadIdx.x >> 6;
    if (lane == 0) ws4[wv] = s;
    __syncthreads();
    if (threadIdx.x == 0)
        out[0] = (ws4[0] + ws4[1] + ws4[2] + ws4[3]) * (1.0f / BATCH);
}

extern "C" void kernel_launch(void* const* d_in, const int* in_sizes, int n_in,
                              void* d_out, int out_size, void* d_ws, size_t ws_size,
                              hipStream_t stream) {
    const float* p1 = (const float*)d_in[0];
    const float* p2 = (const float*)d_in[1];
    uint8_t* ws = (uint8_t*)d_ws;
    chamfer_prep<<<dim3(2 * BATCH * NPTS / 256), dim3(256), 0, stream>>>(p1, p2, ws);
    chamfer_main<<<dim3(NBLK), dim3(BLOCK), 0, stream>>>(p1, p2, ws);
    chamfer_reduce<<<dim3(1), dim3(256), 0, stream>>>(ws, (float*)d_out);
}